// Round 7
// baseline (10546.651 us; speedup 1.0000x reference)
//
#include <hip/hip_runtime.h>
#include <hip/hip_bf16.h>
#include <math.h>

#define D_MODEL 1024
#define D_INNER 2048
#define D_STATE 16
#define D_CONV 4
#define DT_RANK 64
#define N_LAYER 8
#define INPUT_DIM 256
#define BATCH 16
#define TT 64
#define S_IN 13
#define SEQ_S 16                 // S_IN + 3
#define L_SEQ 1024               // TT * SEQ_S
#define XZ_LD (2 * D_INNER)      // 4096
#define PROJ_N 96                // DT_RANK + 2*D_STATE
#define EPS 1e-5f

typedef __attribute__((ext_vector_type(8))) short short8;   // 8 x bf16 (4 VGPRs)
typedef __attribute__((ext_vector_type(4))) float f32x4;    // MFMA acc

// fp32 -> bf16 bits, round-to-nearest-even
__device__ __forceinline__ unsigned short f2bu(float x) {
  unsigned int u = __float_as_uint(x);
  unsigned int r = (u + 0x7fffu + ((u >> 16) & 1u)) >> 16;
  return (unsigned short)r;
}
// bf16 bits -> fp32
__device__ __forceinline__ float bu2f(unsigned short u) {
  return __uint_as_float((unsigned int)u << 16);
}

__device__ __forceinline__ void gload_lds16(const void* g, void* l) {
  __builtin_amdgcn_global_load_lds(
      (const __attribute__((address_space(1))) void*)g,
      (__attribute__((address_space(3))) void*)l, 16, 0, 0);
}

// ---------------------------------------------------------------------------
// bf16 MFMA GEMM: D[M,N] = A[M,K](bf16) @ W[N,K](bf16)^T (+bias)(+act)
// 128x128 tile, BK=32, 4 waves x (4x4 of 16x16x32 MFMA), global_load_lds.
// K-split via gridDim.z (slice z -> C + z*cPartStride).
// Outputs optional: C fp32 (accum: C += v), Cb bf16.
// ---------------------------------------------------------------------------
__global__ __launch_bounds__(256) void gemm_mfma(
    const unsigned short* __restrict__ A, int lda,
    const unsigned short* __restrict__ W, int ldw,
    const float* __restrict__ bias,
    float* __restrict__ C, int ldc, size_t cPartStride, int accum,
    unsigned short* __restrict__ Cb, int ldcb,
    int M, int N, int kLen, int act)
{
  __shared__ unsigned short As[128 * 32];  // 8 KB
  __shared__ unsigned short Ws[128 * 32];  // 8 KB
  const int tid  = threadIdx.x;
  const int wave = tid >> 6;
  const int lane = tid & 63;
  const int m0 = blockIdx.x * 128;
  const int n0 = blockIdx.y * 128;
  const int wm = (wave & 1) * 64;
  const int wn = (wave >> 1) * 64;
  const int kStart = blockIdx.z * kLen;
  if (C) C += (size_t)blockIdx.z * cPartStride;

  const int srow = (lane >> 2);
  const int scol = (lane & 3) * 8;         // bf16 elements

  f32x4 acc[4][4] = {};

  for (int k0 = kStart; k0 < kStart + kLen; k0 += 32) {
#pragma unroll
    for (int i = 0; i < 2; ++i) {
      int rowA = m0 + wave * 32 + i * 16 + srow;
      if (rowA > M - 1) rowA = M - 1;
      gload_lds16(A + (size_t)rowA * lda + k0 + scol,
                  &As[(wave * 32 + i * 16) * 32]);
      int rowW = n0 + wave * 32 + i * 16 + srow;
      if (rowW > N - 1) rowW = N - 1;
      gload_lds16(W + (size_t)rowW * ldw + k0 + scol,
                  &Ws[(wave * 32 + i * 16) * 32]);
    }
    __syncthreads();

    short8 af[4], bf[4];
#pragma unroll
    for (int mi = 0; mi < 4; ++mi)
      af[mi] = *(const short8*)&As[(wm + mi * 16 + (lane & 15)) * 32 + (lane >> 4) * 8];
#pragma unroll
    for (int ni = 0; ni < 4; ++ni)
      bf[ni] = *(const short8*)&Ws[(wn + ni * 16 + (lane & 15)) * 32 + (lane >> 4) * 8];
#pragma unroll
    for (int mi = 0; mi < 4; ++mi)
#pragma unroll
      for (int ni = 0; ni < 4; ++ni)
        acc[mi][ni] = __builtin_amdgcn_mfma_f32_16x16x32_bf16(
            af[mi], bf[ni], acc[mi][ni], 0, 0, 0);
    __syncthreads();
  }

  // epilogue: C/D layout col=lane&15, row=(lane>>4)*4+r   [m89-verified]
#pragma unroll
  for (int mi = 0; mi < 4; ++mi) {
#pragma unroll
    for (int ni = 0; ni < 4; ++ni) {
      const int col = n0 + wn + ni * 16 + (lane & 15);
      if (col >= N) continue;
#pragma unroll
      for (int r = 0; r < 4; ++r) {
        const int row = m0 + wm + mi * 16 + (lane >> 4) * 4 + r;
        if (row >= M) continue;
        float v = acc[mi][ni][r];
        if (bias) v += bias[col];
        if (act == 1) v = (v > 20.f) ? v : log1pf(__expf(v));  // softplus
        if (C) {
          float o = v;
          if (accum) o += C[(size_t)row * ldc + col];
          C[(size_t)row * ldc + col] = o;
        }
        if (Cb) Cb[(size_t)row * ldcb + col] = f2bu(v);
      }
    }
  }
}

// ---------------------------------------------------------------------------
// Sum 4 K-split partials of x_proj -> proj fp32 + projb bf16
// ---------------------------------------------------------------------------
__global__ __launch_bounds__(256) void xproj_combine(
    const float* __restrict__ part, float* __restrict__ proj,
    unsigned short* __restrict__ projb, int n4, size_t stride4)
{
  int i = blockIdx.x * 256 + threadIdx.x;
  if (i >= n4) return;
  float4 a = ((const float4*)part)[i];
  float4 b = ((const float4*)part)[i + stride4];
  float4 c = ((const float4*)part)[i + 2 * stride4];
  float4 d = ((const float4*)part)[i + 3 * stride4];
  float4 v = make_float4(a.x + b.x + c.x + d.x, a.y + b.y + c.y + d.y,
                         a.z + b.z + c.z + d.z, a.w + b.w + c.w + d.w);
  ((float4*)proj)[i] = v;
  ushort4 o;
  o.x = f2bu(v.x); o.y = f2bu(v.y); o.z = f2bu(v.z); o.w = f2bu(v.w);
  ((ushort4*)projb)[i] = o;
}

// ---------------------------------------------------------------------------
// generic fp32 -> bf16 conversion (float4 vectorized)
// ---------------------------------------------------------------------------
__global__ __launch_bounds__(256) void cvt_bf16(
    const float* __restrict__ in, unsigned short* __restrict__ out, int n4)
{
  int i = blockIdx.x * 256 + threadIdx.x;
  if (i < n4) {
    float4 v = ((const float4*)in)[i];
    ushort4 o;
    o.x = f2bu(v.x); o.y = f2bu(v.y); o.z = f2bu(v.z); o.w = f2bu(v.w);
    ((ushort4*)out)[i] = o;
  }
}

// ---------------------------------------------------------------------------
__device__ __forceinline__ float block_reduce_sum_256(float v)
{
  __shared__ float red[4];
#pragma unroll
  for (int off = 32; off > 0; off >>= 1) v += __shfl_xor(v, off, 64);
  const int tid = threadIdx.x;
  if ((tid & 63) == 0) red[tid >> 6] = v;
  __syncthreads();
  return red[0] + red[1] + red[2] + red[3];
}

// ---------------------------------------------------------------------------
// Token assembly: res = concat([cls, h, 0, 0]) + pe   (res carry = hs+res)
// ---------------------------------------------------------------------------
__global__ __launch_bounds__(256) void seq_build(
    const float* __restrict__ hflat, const float* __restrict__ cls,
    float* __restrict__ res)
{
  const int row = blockIdx.x;            // b_local*1024 + l
  const int bl = row >> 10;
  const int l = row & (L_SEQ - 1);
  const int t = l >> 4;
  const int s = l & 15;
  const int tid = threadIdx.x;

  float4 v;
  if (s == 0) {
    v = ((const float4*)cls)[tid];
  } else if (s <= S_IN) {
    const size_t hrow = ((size_t)(bl * TT + t) * S_IN + (s - 1)) * D_MODEL;
    v = ((const float4*)(hflat + hrow))[tid];
  } else {
    v = make_float4(0.f, 0.f, 0.f, 0.f);
  }

  const float cexp = -logf(10000.f) / (float)D_MODEL;
  float pe[4];
#pragma unroll
  for (int j = 0; j < 4; ++j) {
    int d = tid * 4 + j;
    int i2 = d & ~1;
    float ang = (float)t * expf((float)i2 * cexp);
    pe[j] = (d & 1) ? cosf(ang) : sinf(ang);
  }
  v.x += pe[0]; v.y += pe[1]; v.z += pe[2]; v.w += pe[3];

  ((float4*)(res + (size_t)row * D_MODEL))[tid] = v;
}

// ---------------------------------------------------------------------------
// hn(bf16) = rmsnorm(res) * w   (read-only on res; out_proj accumulates res)
// ---------------------------------------------------------------------------
__global__ __launch_bounds__(256) void rmsnorm_only(
    const float* __restrict__ res, unsigned short* __restrict__ hnb,
    const float* __restrict__ w)
{
  const int row = blockIdx.x;
  const int tid = threadIdx.x;
  const size_t base = (size_t)row * D_MODEL;
  float4 r = ((const float4*)(res + base))[tid];
  float ss = r.x * r.x + r.y * r.y + r.z * r.z + r.w * r.w;
  ss = block_reduce_sum_256(ss);
  const float scale = rsqrtf(ss * (1.f / (float)D_MODEL) + EPS);
  float4 wv = ((const float4*)w)[tid];
  ushort4 o;
  o.x = f2bu(r.x * scale * wv.x);
  o.y = f2bu(r.y * scale * wv.y);
  o.z = f2bu(r.z * scale * wv.z);
  o.w = f2bu(r.w * scale * wv.w);
  ((ushort4*)(hnb + base))[tid] = o;
}

// ---------------------------------------------------------------------------
// Depthwise causal conv (K=4) + silu on bf16 xm; 4 channels/thread via
// ushort4 (8 B/lane coalesced taps). Writes u bf16 (xcb).
// Grid: (D_INNER/1024, L_SEQ, bc) x 256 thr.
// ---------------------------------------------------------------------------
__global__ __launch_bounds__(256) void conv_silu(
    const unsigned short* __restrict__ xzb, const float* __restrict__ cw,
    const float* __restrict__ cb, unsigned short* __restrict__ xcb)
{
  const int c = (blockIdx.x * 256 + threadIdx.x) * 4;
  const int t = blockIdx.y;
  const int bl = blockIdx.z;
  const unsigned row = (unsigned)bl * L_SEQ + t;

  // weights for 4 channels: cw[c..c+3][0..3]
  float4 w0 = *(const float4*)&cw[(c + 0) * D_CONV];
  float4 w1 = *(const float4*)&cw[(c + 1) * D_CONV];
  float4 w2 = *(const float4*)&cw[(c + 2) * D_CONV];
  float4 w3 = *(const float4*)&cw[(c + 3) * D_CONV];
  float4 bias = *(const float4*)&cb[c];
  float a0 = bias.x, a1 = bias.y, a2 = bias.z, a3 = bias.w;

#define CONV_TAP(k, wk)                                                      \
  if (t >= 3 - (k)) {                                                        \
    ushort4 xv = *(const ushort4*)&xzb[(size_t)(row - 3 + (k)) * XZ_LD + c]; \
    a0 = fmaf(w0.wk, bu2f(xv.x), a0);                                        \
    a1 = fmaf(w1.wk, bu2f(xv.y), a1);                                        \
    a2 = fmaf(w2.wk, bu2f(xv.z), a2);                                        \
    a3 = fmaf(w3.wk, bu2f(xv.w), a3);                                        \
  }
  CONV_TAP(0, x)
  CONV_TAP(1, y)
  CONV_TAP(2, z)
  CONV_TAP(3, w)
#undef CONV_TAP

  a0 = a0 / (1.f + __expf(-a0));
  a1 = a1 / (1.f + __expf(-a1));
  a2 = a2 / (1.f + __expf(-a2));
  a3 = a3 / (1.f + __expf(-a3));
  ushort4 o;
  o.x = f2bu(a0); o.y = f2bu(a1); o.z = f2bu(a2); o.w = f2bu(a3);
  *(ushort4*)&xcb[(size_t)row * D_INNER + c] = o;
}

// ---------------------------------------------------------------------------
// scan6: 4 states/lane, 4 lanes/channel. VALU-lean addressing: 32-bit
// element offsets bumped by constant strides (replaces per-step 64-bit
// address recompute — R6 post-mortem: addr math was majority of VALU).
// dt/z share one offset (two base ptrs); B/C share one offset (C at +16
// floats = imm offset 64B). 8-slot register pipeline, prefetch distance 7;
// tail via wave-uniform branch (no per-step clamp).
// y bf16 overwrites u in xcb (disjoint elements, wave-synchronous).
// Grid: (D_INNER/64, bc) x 256 thr.
// ---------------------------------------------------------------------------
__global__ __launch_bounds__(256) void scan6(
    const unsigned short* __restrict__ xzb,    // dt half
    const unsigned short* __restrict__ xzbz,   // z half (= xzb + D_INNER)
    unsigned short* xcb,
    const float* __restrict__ proj,
    const float* __restrict__ Alog, const float* __restrict__ Dp)
{
  const int tid  = threadIdx.x;
  const int lane = tid & 63;
  const int wave = tid >> 6;
  const int chl  = lane >> 2;            // channel within wave (0..15)
  const int sq   = lane & 3;             // state quad
  const int ch   = blockIdx.x * 64 + wave * 16 + chl;
  const int s0   = sq * 4;
  const int bl   = blockIdx.y;

  float A[4], h[4] = {0.f, 0.f, 0.f, 0.f};
#pragma unroll
  for (int k = 0; k < 4; ++k)
    A[k] = -__expf(Alog[(size_t)ch * D_STATE + s0 + k]);
  const float Dv = Dp[ch];

  // 32-bit element offsets (max buffer 67M elements < 2^32)
  unsigned odt = (unsigned)bl * (L_SEQ * XZ_LD) + (unsigned)ch;
  unsigned ou  = (unsigned)bl * (L_SEQ * D_INNER) + (unsigned)ch;
  unsigned oB  = (unsigned)bl * (L_SEQ * PROJ_N) + (unsigned)(DT_RANK + s0);
  unsigned ost = ou;                     // store offset (y)

  float pdt[8], pz[8], pu[8];
  float4 pB[8], pC[8];

#define SCAN_LOAD(slot)                                   \
  {                                                       \
    pdt[slot] = bu2f(xzb[odt]);                           \
    pz[slot]  = bu2f(xzbz[odt]);                          \
    pu[slot]  = bu2f(xcb[ou]);                            \
    pB[slot]  = *(const float4*)&proj[oB];                \
    pC[slot]  = *(const float4*)&proj[oB + D_STATE];      \
    odt += XZ_LD; ou += D_INNER; oB += PROJ_N;            \
  }

#pragma unroll
  for (int i = 0; i < 7; ++i) SCAN_LOAD(i)

#pragma unroll 8
  for (int t = 0; t < L_SEQ; ++t) {
    const int sl = t & 7;
    if (t < L_SEQ - 7) SCAN_LOAD((t + 7) & 7)   // wave-uniform branch

    const float dtv = pdt[sl];
    const float u   = pu[sl];
    const float du  = dtv * u;
    const float4 B4 = pB[sl];
    const float4 C4 = pC[sl];
    const float Bk[4] = {B4.x, B4.y, B4.z, B4.w};
    const float Ck[4] = {C4.x, C4.y, C4.z, C4.w};
    float yv = 0.f;
#pragma unroll
    for (int k = 0; k < 4; ++k) {
      const float dA = __expf(dtv * A[k]);
      h[k] = fmaf(dA, h[k], du * Bk[k]);
      yv = fmaf(h[k], Ck[k], yv);
    }
    yv += __shfl_xor(yv, 1, 64);
    yv += __shfl_xor(yv, 2, 64);
    if (sq == 0) {
      const float zv = pz[sl];
      const float g = zv / (1.f + __expf(-zv));     // silu(z)
      xcb[ost] = f2bu(fmaf(Dv, u, yv) * g);
    }
    ost += D_INNER;
  }
#undef SCAN_LOAD
}

// ---------------------------------------------------------------------------
// Final pooled rmsnorm on cls rows (res already holds hs+res)
// ---------------------------------------------------------------------------
__global__ __launch_bounds__(256) void pool_norm(
    const float* __restrict__ res, const float* __restrict__ w,
    float* __restrict__ out, int b0)
{
  const int idx = blockIdx.x;                      // b_local*64 + t
  const int bl = idx >> 6;
  const int t = idx & 63;
  const size_t base = ((size_t)bl * L_SEQ + (size_t)t * SEQ_S) * D_MODEL;
  const int tid = threadIdx.x;
  float4 v = ((const float4*)(res + base))[tid];
  float ss = v.x * v.x + v.y * v.y + v.z * v.z + v.w * v.w;
  ss = block_reduce_sum_256(ss);
  const float scale = rsqrtf(ss * (1.f / (float)D_MODEL) + EPS);
  float4 wv = ((const float4*)w)[tid];
  float4 o = make_float4(v.x * scale * wv.x, v.y * scale * wv.y,
                         v.z * scale * wv.z, v.w * scale * wv.w);
  const size_t orow = (size_t)((b0 + bl) * TT + t) * D_MODEL;
  ((float4*)(out + orow))[tid] = o;
}

// ---------------------------------------------------------------------------
extern "C" void kernel_launch(void* const* d_in, const int* in_sizes, int n_in,
                              void* d_out, int out_size, void* d_ws, size_t ws_size,
                              hipStream_t stream)
{
  const float* x      = (const float*)d_in[0];
  // d_in[1] = tt (int scalar, == 64): compiled in as TT
  const float* w_in   = (const float*)d_in[2];
  const float* b_in   = (const float*)d_in[3];
  const float* cls    = (const float*)d_in[4];
  const float* norm_w = (const float*)d_in[5];
  const float* ipw    = (const float*)d_in[6];
  const float* cw     = (const float*)d_in[7];
  const float* cb     = (const float*)d_in[8];
  const float* xpw    = (const float*)d_in[9];
  const float* dtw    = (const float*)d_in[10];
  const float* dtb    = (const float*)d_in[11];
  const float* Alog   = (const float*)d_in[12];
  const float* Dp     = (const float*)d_in[13];
  const float* opw    = (const float*)d_in[14];
  const float* normfw = (const float*)d_in[15];
  float* out = (float*)d_out;

  // ---- bf16 weight/x region (elements) ----
  const size_t N_WIN = (size_t)D_MODEL * INPUT_DIM;
  const size_t N_IPW = (size_t)N_LAYER * XZ_LD * D_MODEL;
  const size_t N_XPW = (size_t)N_LAYER * PROJ_N * D_INNER;
  const size_t N_DTW = (size_t)N_LAYER * D_INNER * DT_RANK;
  const size_t N_OPW = (size_t)N_LAYER * D_MODEL * D_INNER;
  const size_t N_XB  = (size_t)BATCH * TT * S_IN * INPUT_DIM;
  const size_t N_BF  = N_WIN + N_IPW + N_XPW + N_DTW + N_OPW + N_XB;

  // per-batch activation bytes:
  // res f32 4096 + xzb bf16 8192 + xcb bf16 4096 + proj f32 384
  // + projb bf16 192 + hnb bf16 2048  = 19008 B/row
  const size_t perB = (size_t)L_SEQ * 19008;
  int bc = 0;
  for (int c = 16; c >= 1; c >>= 1)
    if (N_BF * 2 + perB * (size_t)c <= ws_size) { bc = c; break; }
  if (bc == 0) return;

  const int R = bc * L_SEQ;

  unsigned short* w_in_b = (unsigned short*)d_ws;
  unsigned short* ipw_b  = w_in_b + N_WIN;
  unsigned short* xpw_b  = ipw_b + N_IPW;
  unsigned short* dtw_b  = xpw_b + N_XPW;
  unsigned short* opw_b  = dtw_b + N_DTW;
  unsigned short* x_b    = opw_b + N_OPW;
  float*          res  = (float*)(x_b + N_XB);
  unsigned short* xzb  = (unsigned short*)(res + (size_t)R * D_MODEL);
  unsigned short* xcb  = xzb + (size_t)R * XZ_LD;
  float*          proj = (float*)(xcb + (size_t)R * D_INNER);
  unsigned short* projb = (unsigned short*)(proj + (size_t)R * PROJ_N);
  unsigned short* hnb   = projb + (size_t)R * PROJ_N;
  // x_proj K-split partials overlay hnb (dead between in_proj and next
  // rmsnorm): R*384*4 B <= R*2048 B. hflat (input GEMM out) overlays xzb.
  float* ppart = (float*)hnb;
  float* hflat = (float*)xzb;

  // ---- weight + x conversion (once per launch; ws re-poisoned each call) ----
  cvt_bf16<<<(int)((N_WIN/4 + 255)/256), 256, 0, stream>>>(w_in, w_in_b, (int)(N_WIN/4));
  cvt_bf16<<<(int)((N_IPW/4 + 255)/256), 256, 0, stream>>>(ipw, ipw_b, (int)(N_IPW/4));
  cvt_bf16<<<(int)((N_XPW/4 + 255)/256), 256, 0, stream>>>(xpw, xpw_b, (int)(N_XPW/4));
  cvt_bf16<<<(int)((N_DTW/4 + 255)/256), 256, 0, stream>>>(dtw, dtw_b, (int)(N_DTW/4));
  cvt_bf16<<<(int)((N_OPW/4 + 255)/256), 256, 0, stream>>>(opw, opw_b, (int)(N_OPW/4));
  cvt_bf16<<<(int)((N_XB/4  + 255)/256), 256, 0, stream>>>(x,   x_b,   (int)(N_XB/4));

  for (int b0 = 0; b0 < BATCH; b0 += bc) {
    // 1. input projection: hflat = x_chunk @ w_in^T + b_in (fp32, in xzb)
    const int Mx = bc * TT * S_IN;
    gemm_mfma<<<dim3((Mx + 127) / 128, D_MODEL / 128), 256, 0, stream>>>(
        x_b + (size_t)b0 * TT * S_IN * INPUT_DIM, INPUT_DIM,
        w_in_b, INPUT_DIM, b_in, hflat, D_MODEL, 0, 0, nullptr, 0,
        Mx, D_MODEL, INPUT_DIM, 0);

    // 2. token assembly + positional encoding: res = seq
    seq_build<<<R, 256, 0, stream>>>(hflat, cls, res);

    for (int l = 0; l < N_LAYER; ++l) {
      rmsnorm_only<<<R, 256, 0, stream>>>(res, hnb,
          norm_w + (size_t)l * D_MODEL);

      // xzb = bf16(hn @ ipw[l]^T)   (R x 4096, K=1024)
      gemm_mfma<<<dim3(R / 128, XZ_LD / 128), 256, 0, stream>>>(
          hnb, D_MODEL, ipw_b + (size_t)l * XZ_LD * D_MODEL, D_MODEL,
          nullptr, nullptr, 0, 0, 0, xzb, XZ_LD, R, XZ_LD, D_MODEL, 0);

      conv_silu<<<dim3(D_INNER / 1024, L_SEQ, bc), 256, 0, stream>>>(
          xzb, cw + (size_t)l * D_INNER * D_CONV, cb + (size_t)l * D_INNER,
          xcb);

      // x_proj partials: 4-way K-split over K=2048 (hnb window is dead)
      gemm_mfma<<<dim3(R / 128, 1, 4), 256, 0, stream>>>(
          xcb, D_INNER, xpw_b + (size_t)l * PROJ_N * D_INNER, D_INNER,
          nullptr, ppart, PROJ_N, (size_t)R * PROJ_N, 0, nullptr, 0,
          R, PROJ_N, 512, 0);
      xproj_combine<<<(R * PROJ_N / 4 + 255) / 256, 256, 0, stream>>>(
          ppart, proj, projb, R * PROJ_N / 4, (size_t)R * PROJ_N / 4);

      // dt = bf16(softplus(proj[:,:64] @ dtw[l]^T + dtb[l])) -> xm half of xzb
      gemm_mfma<<<dim3(R / 128, D_INNER / 128), 256, 0, stream>>>(
          projb, PROJ_N, dtw_b + (size_t)l * D_INNER * DT_RANK, DT_RANK,
          dtb + (size_t)l * D_INNER, nullptr, 0, 0, 0, xzb, XZ_LD,
          R, D_INNER, 64, 1);

      // selective scan + D-skip + silu(z); y bf16 overwrites u in xcb
      scan6<<<dim3(D_INNER / 64, bc), 256, 0, stream>>>(
          xzb, xzb + D_INNER, xcb, proj,
          Alog + (size_t)l * D_INNER * D_STATE, Dp + (size_t)l * D_INNER);

      // res += y @ opw[l]^T      (R x 1024, K=2048) — accumulate epilogue
      gemm_mfma<<<dim3(R / 128, D_MODEL / 128), 256, 0, stream>>>(
          xcb, D_INNER, opw_b + (size_t)l * D_MODEL * D_INNER, D_INNER,
          nullptr, res, D_MODEL, 0, 1, nullptr, 0, R, D_MODEL, D_INNER, 0);
    }

    pool_norm<<<bc * TT, 256, 0, stream>>>(res, normfw, out, b0);
  }
}

// Round 8
// 8422.814 us; speedup vs baseline: 1.2522x; 1.2522x over previous
//
#include <hip/hip_runtime.h>
#include <hip/hip_bf16.h>
#include <math.h>

#define D_MODEL 1024
#define D_INNER 2048
#define D_STATE 16
#define D_CONV 4
#define DT_RANK 64
#define N_LAYER 8
#define INPUT_DIM 256
#define BATCH 16
#define TT 64
#define S_IN 13
#define SEQ_S 16                 // S_IN + 3
#define L_SEQ 1024               // TT * SEQ_S
#define XZ_LD (2 * D_INNER)      // 4096
#define PROJ_N 96                // DT_RANK + 2*D_STATE
#define EPS 1e-5f

typedef __attribute__((ext_vector_type(8))) short short8;   // 8 x bf16 (4 VGPRs)
typedef __attribute__((ext_vector_type(4))) float f32x4;    // MFMA acc

// fp32 -> bf16 bits, round-to-nearest-even
__device__ __forceinline__ unsigned short f2bu(float x) {
  unsigned int u = __float_as_uint(x);
  unsigned int r = (u + 0x7fffu + ((u >> 16) & 1u)) >> 16;
  return (unsigned short)r;
}
// bf16 bits -> fp32
__device__ __forceinline__ float bu2f(unsigned short u) {
  return __uint_as_float((unsigned int)u << 16);
}

__device__ __forceinline__ void gload_lds16(const void* g, void* l) {
  __builtin_amdgcn_global_load_lds(
      (const __attribute__((address_space(1))) void*)g,
      (__attribute__((address_space(3))) void*)l, 16, 0, 0);
}

// ---------------------------------------------------------------------------
// bf16 MFMA GEMM: D[M,N] = A[M,K](bf16) @ W[N,K](bf16)^T (+bias)(+act)
// 128x128 tile, BK=32, 4 waves x (4x4 of 16x16x32 MFMA), global_load_lds.
// K-split via gridDim.z (slice z -> C + z*cPartStride).
// Outputs optional: C fp32 (accum: C += v), Cb bf16.
// ---------------------------------------------------------------------------
__global__ __launch_bounds__(256) void gemm_mfma(
    const unsigned short* __restrict__ A, int lda,
    const unsigned short* __restrict__ W, int ldw,
    const float* __restrict__ bias,
    float* __restrict__ C, int ldc, size_t cPartStride, int accum,
    unsigned short* __restrict__ Cb, int ldcb,
    int M, int N, int kLen, int act)
{
  __shared__ unsigned short As[128 * 32];  // 8 KB
  __shared__ unsigned short Ws[128 * 32];  // 8 KB
  const int tid  = threadIdx.x;
  const int wave = tid >> 6;
  const int lane = tid & 63;
  const int m0 = blockIdx.x * 128;
  const int n0 = blockIdx.y * 128;
  const int wm = (wave & 1) * 64;
  const int wn = (wave >> 1) * 64;
  const int kStart = blockIdx.z * kLen;
  if (C) C += (size_t)blockIdx.z * cPartStride;

  const int srow = (lane >> 2);
  const int scol = (lane & 3) * 8;         // bf16 elements

  f32x4 acc[4][4] = {};

  for (int k0 = kStart; k0 < kStart + kLen; k0 += 32) {
#pragma unroll
    for (int i = 0; i < 2; ++i) {
      int rowA = m0 + wave * 32 + i * 16 + srow;
      if (rowA > M - 1) rowA = M - 1;
      gload_lds16(A + (size_t)rowA * lda + k0 + scol,
                  &As[(wave * 32 + i * 16) * 32]);
      int rowW = n0 + wave * 32 + i * 16 + srow;
      if (rowW > N - 1) rowW = N - 1;
      gload_lds16(W + (size_t)rowW * ldw + k0 + scol,
                  &Ws[(wave * 32 + i * 16) * 32]);
    }
    __syncthreads();

    short8 af[4], bf[4];
#pragma unroll
    for (int mi = 0; mi < 4; ++mi)
      af[mi] = *(const short8*)&As[(wm + mi * 16 + (lane & 15)) * 32 + (lane >> 4) * 8];
#pragma unroll
    for (int ni = 0; ni < 4; ++ni)
      bf[ni] = *(const short8*)&Ws[(wn + ni * 16 + (lane & 15)) * 32 + (lane >> 4) * 8];
#pragma unroll
    for (int mi = 0; mi < 4; ++mi)
#pragma unroll
      for (int ni = 0; ni < 4; ++ni)
        acc[mi][ni] = __builtin_amdgcn_mfma_f32_16x16x32_bf16(
            af[mi], bf[ni], acc[mi][ni], 0, 0, 0);
    __syncthreads();
  }

  // epilogue: C/D layout col=lane&15, row=(lane>>4)*4+r   [m89-verified]
#pragma unroll
  for (int mi = 0; mi < 4; ++mi) {
#pragma unroll
    for (int ni = 0; ni < 4; ++ni) {
      const int col = n0 + wn + ni * 16 + (lane & 15);
      if (col >= N) continue;
#pragma unroll
      for (int r = 0; r < 4; ++r) {
        const int row = m0 + wm + mi * 16 + (lane >> 4) * 4 + r;
        if (row >= M) continue;
        float v = acc[mi][ni][r];
        if (bias) v += bias[col];
        if (act == 1) v = (v > 20.f) ? v : log1pf(__expf(v));  // softplus
        if (C) {
          float o = v;
          if (accum) o += C[(size_t)row * ldc + col];
          C[(size_t)row * ldc + col] = o;
        }
        if (Cb) Cb[(size_t)row * ldcb + col] = f2bu(v);
      }
    }
  }
}

// ---------------------------------------------------------------------------
// Sum 4 K-split partials of x_proj -> proj fp32 + projb bf16
// ---------------------------------------------------------------------------
__global__ __launch_bounds__(256) void xproj_combine(
    const float* __restrict__ part, float* __restrict__ proj,
    unsigned short* __restrict__ projb, int n4, size_t stride4)
{
  int i = blockIdx.x * 256 + threadIdx.x;
  if (i >= n4) return;
  float4 a = ((const float4*)part)[i];
  float4 b = ((const float4*)part)[i + stride4];
  float4 c = ((const float4*)part)[i + 2 * stride4];
  float4 d = ((const float4*)part)[i + 3 * stride4];
  float4 v = make_float4(a.x + b.x + c.x + d.x, a.y + b.y + c.y + d.y,
                         a.z + b.z + c.z + d.z, a.w + b.w + c.w + d.w);
  ((float4*)proj)[i] = v;
  ushort4 o;
  o.x = f2bu(v.x); o.y = f2bu(v.y); o.z = f2bu(v.z); o.w = f2bu(v.w);
  ((ushort4*)projb)[i] = o;
}

// ---------------------------------------------------------------------------
// generic fp32 -> bf16 conversion (float4 vectorized)
// ---------------------------------------------------------------------------
__global__ __launch_bounds__(256) void cvt_bf16(
    const float* __restrict__ in, unsigned short* __restrict__ out, int n4)
{
  int i = blockIdx.x * 256 + threadIdx.x;
  if (i < n4) {
    float4 v = ((const float4*)in)[i];
    ushort4 o;
    o.x = f2bu(v.x); o.y = f2bu(v.y); o.z = f2bu(v.z); o.w = f2bu(v.w);
    ((ushort4*)out)[i] = o;
  }
}

// ---------------------------------------------------------------------------
__device__ __forceinline__ float block_reduce_sum_256(float v)
{
  __shared__ float red[4];
#pragma unroll
  for (int off = 32; off > 0; off >>= 1) v += __shfl_xor(v, off, 64);
  const int tid = threadIdx.x;
  if ((tid & 63) == 0) red[tid >> 6] = v;
  __syncthreads();
  return red[0] + red[1] + red[2] + red[3];
}

// ---------------------------------------------------------------------------
// Token assembly: res = concat([cls, h, 0, 0]) + pe   (res carry = hs+res)
// ---------------------------------------------------------------------------
__global__ __launch_bounds__(256) void seq_build(
    const float* __restrict__ hflat, const float* __restrict__ cls,
    float* __restrict__ res)
{
  const int row = blockIdx.x;            // b_local*1024 + l
  const int bl = row >> 10;
  const int l = row & (L_SEQ - 1);
  const int t = l >> 4;
  const int s = l & 15;
  const int tid = threadIdx.x;

  float4 v;
  if (s == 0) {
    v = ((const float4*)cls)[tid];
  } else if (s <= S_IN) {
    const size_t hrow = ((size_t)(bl * TT + t) * S_IN + (s - 1)) * D_MODEL;
    v = ((const float4*)(hflat + hrow))[tid];
  } else {
    v = make_float4(0.f, 0.f, 0.f, 0.f);
  }

  const float cexp = -logf(10000.f) / (float)D_MODEL;
  float pe[4];
#pragma unroll
  for (int j = 0; j < 4; ++j) {
    int d = tid * 4 + j;
    int i2 = d & ~1;
    float ang = (float)t * expf((float)i2 * cexp);
    pe[j] = (d & 1) ? cosf(ang) : sinf(ang);
  }
  v.x += pe[0]; v.y += pe[1]; v.z += pe[2]; v.w += pe[3];

  ((float4*)(res + (size_t)row * D_MODEL))[tid] = v;
}

// ---------------------------------------------------------------------------
// hn(bf16) = rmsnorm(res) * w   (read-only on res; out_proj accumulates res)
// ---------------------------------------------------------------------------
__global__ __launch_bounds__(256) void rmsnorm_only(
    const float* __restrict__ res, unsigned short* __restrict__ hnb,
    const float* __restrict__ w)
{
  const int row = blockIdx.x;
  const int tid = threadIdx.x;
  const size_t base = (size_t)row * D_MODEL;
  float4 r = ((const float4*)(res + base))[tid];
  float ss = r.x * r.x + r.y * r.y + r.z * r.z + r.w * r.w;
  ss = block_reduce_sum_256(ss);
  const float scale = rsqrtf(ss * (1.f / (float)D_MODEL) + EPS);
  float4 wv = ((const float4*)w)[tid];
  ushort4 o;
  o.x = f2bu(r.x * scale * wv.x);
  o.y = f2bu(r.y * scale * wv.y);
  o.z = f2bu(r.z * scale * wv.z);
  o.w = f2bu(r.w * scale * wv.w);
  ((ushort4*)(hnb + base))[tid] = o;
}

// ---------------------------------------------------------------------------
// Depthwise causal conv (K=4) + silu on bf16 xm; 4 channels/thread via
// ushort4 (8 B/lane coalesced taps). Writes u bf16 (xcb).
// Grid: (D_INNER/1024, L_SEQ, bc) x 256 thr.
// ---------------------------------------------------------------------------
__global__ __launch_bounds__(256) void conv_silu(
    const unsigned short* __restrict__ xzb, const float* __restrict__ cw,
    const float* __restrict__ cb, unsigned short* __restrict__ xcb)
{
  const int c = (blockIdx.x * 256 + threadIdx.x) * 4;
  const int t = blockIdx.y;
  const int bl = blockIdx.z;
  const unsigned row = (unsigned)bl * L_SEQ + t;

  float4 w0 = *(const float4*)&cw[(c + 0) * D_CONV];
  float4 w1 = *(const float4*)&cw[(c + 1) * D_CONV];
  float4 w2 = *(const float4*)&cw[(c + 2) * D_CONV];
  float4 w3 = *(const float4*)&cw[(c + 3) * D_CONV];
  float4 bias = *(const float4*)&cb[c];
  float a0 = bias.x, a1 = bias.y, a2 = bias.z, a3 = bias.w;

#define CONV_TAP(k, wk)                                                      \
  if (t >= 3 - (k)) {                                                        \
    ushort4 xv = *(const ushort4*)&xzb[(size_t)(row - 3 + (k)) * XZ_LD + c]; \
    a0 = fmaf(w0.wk, bu2f(xv.x), a0);                                        \
    a1 = fmaf(w1.wk, bu2f(xv.y), a1);                                        \
    a2 = fmaf(w2.wk, bu2f(xv.z), a2);                                        \
    a3 = fmaf(w3.wk, bu2f(xv.w), a3);                                        \
  }
  CONV_TAP(0, x)
  CONV_TAP(1, y)
  CONV_TAP(2, z)
  CONV_TAP(3, w)
#undef CONV_TAP

  a0 = a0 / (1.f + __expf(-a0));
  a1 = a1 / (1.f + __expf(-a1));
  a2 = a2 / (1.f + __expf(-a2));
  a3 = a3 / (1.f + __expf(-a3));
  ushort4 o;
  o.x = f2bu(a0); o.y = f2bu(a1); o.z = f2bu(a2); o.w = f2bu(a3);
  *(ushort4*)&xcb[(size_t)row * D_INNER + c] = o;
}

// ---------------------------------------------------------------------------
// scan7: scan5 structure (4 slots, distance 3, unroll 4, UNCONDITIONAL
// loads) with byte-offset addressing: 32-bit byte offsets on char* bases,
// bumped by constant strides -> saddr+voffset global loads instead of
// per-step 64-bit address recompute (R7 post-mortem: conditional prefetch
// + reg arrays broke scheduling; VALU work was unchanged by elem offsets).
// Tail prefetches read <=3 rows past the region into the adjacent mapped
// workspace buffer; those slots are never consumed.
// A pre-scaled by log2e -> exp2f (v_exp_f32 is a base-2 op; saves 4 muls).
// y bf16 overwrites u in xcb (disjoint elements, wave-synchronous).
// Grid: (D_INNER/64, bc) x 256 thr.
// ---------------------------------------------------------------------------
__global__ __launch_bounds__(256) void scan7(
    const unsigned short* __restrict__ xzb,    // dt half
    const unsigned short* __restrict__ xzbz,   // z half (= xzb + D_INNER)
    unsigned short* xcb,
    const float* __restrict__ proj,
    const float* __restrict__ Alog, const float* __restrict__ Dp)
{
  const int tid  = threadIdx.x;
  const int lane = tid & 63;
  const int wave = tid >> 6;
  const int chl  = lane >> 2;            // channel within wave (0..15)
  const int sq   = lane & 3;             // state quad
  const int ch   = blockIdx.x * 64 + wave * 16 + chl;
  const int s0   = sq * 4;
  const int bl   = blockIdx.y;

  float A2[4], h[4] = {0.f, 0.f, 0.f, 0.f};
#pragma unroll
  for (int k = 0; k < 4; ++k)
    A2[k] = -__expf(Alog[(size_t)ch * D_STATE + s0 + k]) * 1.44269504f;
  const float Dv = Dp[ch];

  // 32-bit BYTE offsets (max region 134 MB < 4 GB), constant-stride bumps
  unsigned odt = ((unsigned)bl * (L_SEQ * XZ_LD) + (unsigned)ch) * 2u;
  unsigned ou  = ((unsigned)bl * (L_SEQ * D_INNER) + (unsigned)ch) * 2u;
  unsigned oB  = ((unsigned)bl * (L_SEQ * PROJ_N) + (unsigned)(DT_RANK + s0)) * 4u;
  unsigned ost = ou;                     // store offset (y)

  float pdt[4], pz[4], pu[4];
  float4 pB[4], pC[4];

#define SCAN_LOAD(slot)                                                       \
  {                                                                           \
    pdt[slot] = bu2f(*(const unsigned short*)((const char*)xzb + odt));       \
    pz[slot]  = bu2f(*(const unsigned short*)((const char*)xzbz + odt));      \
    pu[slot]  = bu2f(*(const unsigned short*)((const char*)xcb + ou));        \
    pB[slot]  = *(const float4*)((const char*)proj + oB);                     \
    pC[slot]  = *(const float4*)((const char*)proj + oB + D_STATE * 4);       \
    odt += XZ_LD * 2; ou += D_INNER * 2; oB += PROJ_N * 4;                    \
  }

  SCAN_LOAD(0)
  SCAN_LOAD(1)
  SCAN_LOAD(2)

#pragma unroll 4
  for (int t = 0; t < L_SEQ; ++t) {
    const int sl = t & 3;
    SCAN_LOAD((t + 3) & 3)               // unconditional; tail reads unused

    const float dtv = pdt[sl];
    const float u   = pu[sl];
    const float du  = dtv * u;
    const float4 B4 = pB[sl];
    const float4 C4 = pC[sl];
    const float Bk[4] = {B4.x, B4.y, B4.z, B4.w};
    const float Ck[4] = {C4.x, C4.y, C4.z, C4.w};
    float yv = 0.f;
#pragma unroll
    for (int k = 0; k < 4; ++k) {
      const float dA = exp2f(dtv * A2[k]);           // v_mul + v_exp
      h[k] = fmaf(dA, h[k], du * Bk[k]);
      yv = fmaf(h[k], Ck[k], yv);
    }
    yv += __shfl_xor(yv, 1, 64);
    yv += __shfl_xor(yv, 2, 64);
    if (sq == 0) {
      const float zv = pz[sl];
      const float g = zv / (1.f + __expf(-zv));      // silu(z)
      *(unsigned short*)((char*)xcb + ost) = f2bu(fmaf(Dv, u, yv) * g);
    }
    ost += D_INNER * 2;
  }
#undef SCAN_LOAD
}

// ---------------------------------------------------------------------------
// Final pooled rmsnorm on cls rows (res already holds hs+res)
// ---------------------------------------------------------------------------
__global__ __launch_bounds__(256) void pool_norm(
    const float* __restrict__ res, const float* __restrict__ w,
    float* __restrict__ out, int b0)
{
  const int idx = blockIdx.x;                      // b_local*64 + t
  const int bl = idx >> 6;
  const int t = idx & 63;
  const size_t base = ((size_t)bl * L_SEQ + (size_t)t * SEQ_S) * D_MODEL;
  const int tid = threadIdx.x;
  float4 v = ((const float4*)(res + base))[tid];
  float ss = v.x * v.x + v.y * v.y + v.z * v.z + v.w * v.w;
  ss = block_reduce_sum_256(ss);
  const float scale = rsqrtf(ss * (1.f / (float)D_MODEL) + EPS);
  float4 wv = ((const float4*)w)[tid];
  float4 o = make_float4(v.x * scale * wv.x, v.y * scale * wv.y,
                         v.z * scale * wv.z, v.w * scale * wv.w);
  const size_t orow = (size_t)((b0 + bl) * TT + t) * D_MODEL;
  ((float4*)(out + orow))[tid] = o;
}

// ---------------------------------------------------------------------------
extern "C" void kernel_launch(void* const* d_in, const int* in_sizes, int n_in,
                              void* d_out, int out_size, void* d_ws, size_t ws_size,
                              hipStream_t stream)
{
  const float* x      = (const float*)d_in[0];
  // d_in[1] = tt (int scalar, == 64): compiled in as TT
  const float* w_in   = (const float*)d_in[2];
  const float* b_in   = (const float*)d_in[3];
  const float* cls    = (const float*)d_in[4];
  const float* norm_w = (const float*)d_in[5];
  const float* ipw    = (const float*)d_in[6];
  const float* cw     = (const float*)d_in[7];
  const float* cb     = (const float*)d_in[8];
  const float* xpw    = (const float*)d_in[9];
  const float* dtw    = (const float*)d_in[10];
  const float* dtb    = (const float*)d_in[11];
  const float* Alog   = (const float*)d_in[12];
  const float* Dp     = (const float*)d_in[13];
  const float* opw    = (const float*)d_in[14];
  const float* normfw = (const float*)d_in[15];
  float* out = (float*)d_out;

  // ---- bf16 weight/x region (elements) ----
  const size_t N_WIN = (size_t)D_MODEL * INPUT_DIM;
  const size_t N_IPW = (size_t)N_LAYER * XZ_LD * D_MODEL;
  const size_t N_XPW = (size_t)N_LAYER * PROJ_N * D_INNER;
  const size_t N_DTW = (size_t)N_LAYER * D_INNER * DT_RANK;
  const size_t N_OPW = (size_t)N_LAYER * D_MODEL * D_INNER;
  const size_t N_XB  = (size_t)BATCH * TT * S_IN * INPUT_DIM;
  const size_t N_BF  = N_WIN + N_IPW + N_XPW + N_DTW + N_OPW + N_XB;

  // per-batch activation bytes:
  // res f32 4096 + xzb bf16 8192 + xcb bf16 4096 + proj f32 384
  // + projb bf16 192 + hnb bf16 2048  = 19008 B/row
  const size_t perB = (size_t)L_SEQ * 19008;
  int bc = 0;
  for (int c = 16; c >= 1; c >>= 1)
    if (N_BF * 2 + perB * (size_t)c <= ws_size) { bc = c; break; }
  if (bc == 0) return;

  const int R = bc * L_SEQ;

  unsigned short* w_in_b = (unsigned short*)d_ws;
  unsigned short* ipw_b  = w_in_b + N_WIN;
  unsigned short* xpw_b  = ipw_b + N_IPW;
  unsigned short* dtw_b  = xpw_b + N_XPW;
  unsigned short* opw_b  = dtw_b + N_DTW;
  unsigned short* x_b    = opw_b + N_OPW;
  float*          res  = (float*)(x_b + N_XB);
  unsigned short* xzb  = (unsigned short*)(res + (size_t)R * D_MODEL);
  unsigned short* xcb  = xzb + (size_t)R * XZ_LD;
  float*          proj = (float*)(xcb + (size_t)R * D_INNER);
  unsigned short* projb = (unsigned short*)(proj + (size_t)R * PROJ_N);
  unsigned short* hnb   = projb + (size_t)R * PROJ_N;
  // x_proj K-split partials overlay hnb (dead between in_proj and next
  // rmsnorm): R*384*4 B <= R*2048 B. hflat (input GEMM out) overlays xzb.
  float* ppart = (float*)hnb;
  float* hflat = (float*)xzb;

  // ---- weight + x conversion (once per launch; ws re-poisoned each call) ----
  cvt_bf16<<<(int)((N_WIN/4 + 255)/256), 256, 0, stream>>>(w_in, w_in_b, (int)(N_WIN/4));
  cvt_bf16<<<(int)((N_IPW/4 + 255)/256), 256, 0, stream>>>(ipw, ipw_b, (int)(N_IPW/4));
  cvt_bf16<<<(int)((N_XPW/4 + 255)/256), 256, 0, stream>>>(xpw, xpw_b, (int)(N_XPW/4));
  cvt_bf16<<<(int)((N_DTW/4 + 255)/256), 256, 0, stream>>>(dtw, dtw_b, (int)(N_DTW/4));
  cvt_bf16<<<(int)((N_OPW/4 + 255)/256), 256, 0, stream>>>(opw, opw_b, (int)(N_OPW/4));
  cvt_bf16<<<(int)((N_XB/4  + 255)/256), 256, 0, stream>>>(x,   x_b,   (int)(N_XB/4));

  for (int b0 = 0; b0 < BATCH; b0 += bc) {
    // 1. input projection: hflat = x_chunk @ w_in^T + b_in (fp32, in xzb)
    const int Mx = bc * TT * S_IN;
    gemm_mfma<<<dim3((Mx + 127) / 128, D_MODEL / 128), 256, 0, stream>>>(
        x_b + (size_t)b0 * TT * S_IN * INPUT_DIM, INPUT_DIM,
        w_in_b, INPUT_DIM, b_in, hflat, D_MODEL, 0, 0, nullptr, 0,
        Mx, D_MODEL, INPUT_DIM, 0);

    // 2. token assembly + positional encoding: res = seq
    seq_build<<<R, 256, 0, stream>>>(hflat, cls, res);

    for (int l = 0; l < N_LAYER; ++l) {
      rmsnorm_only<<<R, 256, 0, stream>>>(res, hnb,
          norm_w + (size_t)l * D_MODEL);

      // xzb = bf16(hn @ ipw[l]^T)   (R x 4096, K=1024)
      gemm_mfma<<<dim3(R / 128, XZ_LD / 128), 256, 0, stream>>>(
          hnb, D_MODEL, ipw_b + (size_t)l * XZ_LD * D_MODEL, D_MODEL,
          nullptr, nullptr, 0, 0, 0, xzb, XZ_LD, R, XZ_LD, D_MODEL, 0);

      conv_silu<<<dim3(D_INNER / 1024, L_SEQ, bc), 256, 0, stream>>>(
          xzb, cw + (size_t)l * D_INNER * D_CONV, cb + (size_t)l * D_INNER,
          xcb);

      // x_proj partials: 4-way K-split over K=2048 (hnb window is dead)
      gemm_mfma<<<dim3(R / 128, 1, 4), 256, 0, stream>>>(
          xcb, D_INNER, xpw_b + (size_t)l * PROJ_N * D_INNER, D_INNER,
          nullptr, ppart, PROJ_N, (size_t)R * PROJ_N, 0, nullptr, 0,
          R, PROJ_N, 512, 0);
      xproj_combine<<<(R * PROJ_N / 4 + 255) / 256, 256, 0, stream>>>(
          ppart, proj, projb, R * PROJ_N / 4, (size_t)R * PROJ_N / 4);

      // dt = bf16(softplus(proj[:,:64] @ dtw[l]^T + dtb[l])) -> xm half of xzb
      gemm_mfma<<<dim3(R / 128, D_INNER / 128), 256, 0, stream>>>(
          projb, PROJ_N, dtw_b + (size_t)l * D_INNER * DT_RANK, DT_RANK,
          dtb + (size_t)l * D_INNER, nullptr, 0, 0, 0, xzb, XZ_LD,
          R, D_INNER, 64, 1);

      // selective scan + D-skip + silu(z); y bf16 overwrites u in xcb
      scan7<<<dim3(D_INNER / 64, bc), 256, 0, stream>>>(
          xzb, xzb + D_INNER, xcb, proj,
          Alog + (size_t)l * D_INNER * D_STATE, Dp + (size_t)l * D_INNER);

      // res += y @ opw[l]^T      (R x 1024, K=2048) — accumulate epilogue
      gemm_mfma<<<dim3(R / 128, D_MODEL / 128), 256, 0, stream>>>(
          xcb, D_INNER, opw_b + (size_t)l * D_MODEL * D_INNER, D_INNER,
          nullptr, res, D_MODEL, 0, 1, nullptr, 0, R, D_MODEL, D_INNER, 0);
    }

    pool_norm<<<bc * TT, 256, 0, stream>>>(res, normfw, out, b0);
  }
}